// Round 24
// baseline (127.982 us; speedup 1.0000x reference)
//
#include <hip/hip_runtime.h>
#include <hip/hip_bf16.h>

// MHA forward. f32 inputs (+int32 mask), f32 output; bf16 internal pipeline.
// B=2, S=2048, D_MODEL=1024, H=16, DK=64.
// R24 = r23 + pre-convert q,k -> bf16 in d_out scratch (v stays f32):
// QKV A-staging becomes pure-bf16 for z in {0,1}.
// [cvt_w] -> [cvt_in q,k -> d_out] -> [QKV GEMM z=3] -> [attn r17] ->
// [cvt_w wo] -> [O proj 64x128 (overwrites d_out with final result)].

typedef short short8  __attribute__((ext_vector_type(8)));
typedef short short4v __attribute__((ext_vector_type(4)));
typedef float f32x4   __attribute__((ext_vector_type(4)));

#define D_MODEL 1024
#define SEQ     2048
#define NHEAD   16
#define DKD     64
#define HSTR    (SEQ * DKD)
#define QSCALE  0.1803368801111204f   // 0.125 * log2(e): exp2-domain softmax
#define EXP2F(x) __builtin_amdgcn_exp2f(x)   // raw v_exp_f32 (base-2 HW exp)

#define MFMA16(a, b, c) __builtin_amdgcn_mfma_f32_16x16x32_bf16((a), (b), (c), 0, 0, 0)

__device__ __forceinline__ ushort f2bf(float f) {
    __hip_bfloat16 h = __float2bfloat16(f);   // RNE
    return __builtin_bit_cast(ushort, h);
}

__device__ __forceinline__ short8 frag128(const ushort* base, int row, int c0) {
    int cb = (c0 * 2) ^ ((row & 7) << 4);
    return *(const short8*)((const char*)base + row * 128 + cb);
}
__device__ __forceinline__ short8 frag256(const ushort* base, int row, int c0) {
    int cb = (c0 * 2) ^ ((row & 7) << 4);
    return *(const short8*)((const char*)base + row * 256 + cb);
}

// ---------------------------------------------------------------------------
// f32 -> bf16 weight pre-convert: 1M elems per z-slice. grid (512, nz) x 256.
// ---------------------------------------------------------------------------
__global__ __launch_bounds__(256) void cvt_w(
    const float* __restrict__ s0, const float* __restrict__ s1, const float* __restrict__ s2,
    ushort* __restrict__ dst)
{
    const int z = blockIdx.y;
    const float* s = (z == 0) ? s0 : ((z == 1) ? s1 : s2);
    ushort* d = dst + (size_t)z * 1048576;
    const int i = (blockIdx.x * 256 + threadIdx.x) * 8;
    f32x4 a = *(const f32x4*)(s + i);
    f32x4 b = *(const f32x4*)(s + i + 4);
    short8 o;
    #pragma unroll
    for (int u = 0; u < 4; ++u) { o[u] = (short)f2bf(a[u]); o[4 + u] = (short)f2bf(b[u]); }
    *(short8*)(d + i) = o;
}

// ---------------------------------------------------------------------------
// f32 -> bf16 input pre-convert: 4M elems per z-slice (q, k). grid (2048, 2).
// ---------------------------------------------------------------------------
__global__ __launch_bounds__(256) void cvt_in(
    const float* __restrict__ s0, const float* __restrict__ s1, ushort* __restrict__ dst)
{
    const int z = blockIdx.y;
    const float* s = (z == 0) ? s0 : s1;
    ushort* d = dst + (size_t)z * 4194304;
    const int i = (blockIdx.x * 256 + threadIdx.x) * 8;
    f32x4 a = *(const f32x4*)(s + i);
    f32x4 b = *(const f32x4*)(s + i + 4);
    short8 o;
    #pragma unroll
    for (int u = 0; u < 4; ++u) { o[u] = (short)f2bf(a[u]); o[4 + u] = (short)f2bf(b[u]); }
    *(short8*)(d + i) = o;
}

// ---------------------------------------------------------------------------
// QKV GEMM: tile 128x128, BK=64, T14 1-deep prefetch. W bf16.
// z==0 Q (A bf16, scaled, head-split); z==1 K (A bf16, head-split);
// z==2 V (A f32 + inline cvt, transposed via LDS epilogue).
// ---------------------------------------------------------------------------
__global__ __launch_bounds__(256, 3) void gemm_qkv(
    const ushort* __restrict__ A0, const ushort* __restrict__ A1, const float* __restrict__ A2,
    const ushort* __restrict__ W0, const ushort* __restrict__ W1, const ushort* __restrict__ W2,
    ushort* __restrict__ O0, ushort* __restrict__ O1, ushort* __restrict__ O2)
{
    const int z = blockIdx.z;
    const ushort* Ab = (z == 0) ? A0 : A1;         // bf16 A (z<2)
    const ushort* W  = (z == 0) ? W0 : ((z == 1) ? W1 : W2);
    ushort* O        = (z == 0) ? O0 : ((z == 1) ? O1 : O2);

    const int bm = blockIdx.x * 128;
    const int bn = blockIdx.y * 128;
    const int tid = threadIdx.x;
    const int w = tid >> 6, l = tid & 63;
    const int wr = w >> 1, wc = w & 1;

    __shared__ ushort sm[16384];

    f32x4 acc[4][4] = {};
    short8 areg[4], wreg[4];
    const int srow = tid >> 3;
    const int sc8  = (tid & 7) << 3;
    const int scb  = (sc8 * 2);

    #define GLOADT(t_) {                                                                    \
        if (z == 2) {                                                                       \
            _Pragma("unroll")                                                               \
            for (int i = 0; i < 4; ++i) {                                                   \
                int row = i * 32 + srow;                                                    \
                const float* ap = A2 + (size_t)(bm + row) * 1024 + (t_) * 64 + sc8;         \
                f32x4 x0 = *(const f32x4*)ap, x1 = *(const f32x4*)(ap + 4);                 \
                _Pragma("unroll")                                                           \
                for (int u = 0; u < 4; ++u) { areg[i][u] = (short)f2bf(x0[u]); areg[i][4 + u] = (short)f2bf(x1[u]); } \
            }                                                                               \
        } else {                                                                            \
            _Pragma("unroll")                                                               \
            for (int i = 0; i < 4; ++i) {                                                   \
                int row = i * 32 + srow;                                                    \
                areg[i] = *(const short8*)(Ab + (size_t)(bm + row) * 1024 + (t_) * 64 + sc8); \
            }                                                                               \
        }                                                                                   \
        _Pragma("unroll")                                                                   \
        for (int i = 0; i < 4; ++i) {                                                       \
            int row = i * 32 + srow;                                                        \
            wreg[i] = *(const short8*)(W + (size_t)(bn + row) * 1024 + (t_) * 64 + sc8);    \
        } }

    #define GWRITET() {                                                                     \
        _Pragma("unroll")                                                                   \
        for (int i = 0; i < 4; ++i) {                                                       \
            int row = i * 32 + srow;                                                        \
            int cb  = scb ^ ((row & 7) << 4);                                               \
            *(short8*)((char*)sm + row * 128 + cb) = areg[i];                               \
            *(short8*)((char*)(sm + 8192) + row * 128 + cb) = wreg[i];                      \
        } }

    GLOADT(0);
    #pragma unroll 1
    for (int t = 0; t < 16; ++t) {
        GWRITET();
        __syncthreads();
        if (t < 15) GLOADT(t + 1);

        #pragma unroll
        for (int kk = 0; kk < 2; ++kk) {
            const int c0 = kk * 32 + ((l >> 4) << 3);
            short8 af[4], bf[4];
            #pragma unroll
            for (int mi = 0; mi < 4; ++mi)
                af[mi] = frag128(sm, wr * 64 + mi * 16 + (l & 15), c0);
            #pragma unroll
            for (int ni = 0; ni < 4; ++ni)
                bf[ni] = frag128(sm + 8192, wc * 64 + ni * 16 + (l & 15), c0);
            #pragma unroll
            for (int mi = 0; mi < 4; ++mi)
                #pragma unroll
                for (int ni = 0; ni < 4; ++ni)
                    acc[mi][ni] = MFMA16(af[mi], bf[ni], acc[mi][ni]);
        }
        __syncthreads();
    }
    #undef GLOADT
    #undef GWRITET

    if (z == 2) {
        // V epilogue: transpose in LDS, write [bh][dk][s] with 128B-contiguous runs.
        #pragma unroll
        for (int mi = 0; mi < 4; ++mi) {
            #pragma unroll
            for (int ni = 0; ni < 4; ++ni) {
                int n_l = wc * 64 + ni * 16 + (l & 15);
                int m0  = wr * 64 + mi * 16 + ((l >> 4) << 2);
                short4v v4;
                #pragma unroll
                for (int j = 0; j < 4; ++j) v4[j] = (short)f2bf(acc[mi][ni][j]);
                *(short4v*)((char*)sm + n_l * 256 + ((m0 * 2) ^ ((n_l & 7) << 4))) = v4;
            }
        }
        __syncthreads();
        const int row = tid >> 1, half = tid & 1;
        const int n_g = bn + row;
        const int bb  = bm >> 11;
        ushort* Op = O + (size_t)(bb * NHEAD + (n_g >> 6)) * HSTR
                     + (size_t)(n_g & 63) * SEQ + (bm & 2047) + half * 64;
        #pragma unroll
        for (int u = 0; u < 8; ++u) {
            short8 c = *(const short8*)((char*)sm + row * 256
                        + (((half * 64 + u * 8) * 2) ^ ((row & 7) << 4)));
            *(short8*)(Op + u * 8) = c;
        }
        return;
    }

    const float sc = (z == 0) ? QSCALE : 1.0f;
    #pragma unroll
    for (int mi = 0; mi < 4; ++mi) {
        #pragma unroll
        for (int ni = 0; ni < 4; ++ni) {
            #pragma unroll
            for (int j = 0; j < 4; ++j) {
                int m = bm + wr * 64 + mi * 16 + ((l >> 4) << 2) + j;
                int n = bn + wc * 64 + ni * 16 + (l & 15);
                int b = m >> 11, s = m & 2047, h = n >> 6, dk = n & 63;
                O[(size_t)(b * NHEAD + h) * HSTR + s * DKD + dk] = f2bf(acc[mi][ni][j] * sc);
            }
        }
    }
}

// ---------------------------------------------------------------------------
// O-proj GEMM (r23): tile 64x128, BK=64, T14 prefetch. A,W bf16 -> f32 out.
// ---------------------------------------------------------------------------
__global__ __launch_bounds__(256, 5) void gemm_o(
    const ushort* __restrict__ A, const ushort* __restrict__ W, float* __restrict__ O)
{
    const int bm = blockIdx.x * 64;
    const int bn = blockIdx.y * 128;
    const int tid = threadIdx.x;
    const int w = tid >> 6, l = tid & 63;
    const int hi = l >> 4, lo = l & 15;
    const int wr = w >> 1, wc = w & 1;

    __shared__ ushort sm[12288];    // A [64][64] @0 (8KB), W [128][64] @4096 (16KB)

    f32x4 acc[2][4] = {};
    short8 areg[2], wreg[4];
    const int srow = tid >> 3;              // 0..31
    const int sc8  = (tid & 7) << 3;
    const int scb  = sc8 * 2;

    #define OLOADT(t_) {                                                                    \
        _Pragma("unroll")                                                                   \
        for (int i = 0; i < 2; ++i) {                                                       \
            int row = i * 32 + srow;                                                        \
            areg[i] = *(const short8*)(A + (size_t)(bm + row) * 1024 + (t_) * 64 + sc8);    \
        }                                                                                   \
        _Pragma("unroll")                                                                   \
        for (int i = 0; i < 4; ++i) {                                                       \
            int row = i * 32 + srow;                                                        \
            wreg[i] = *(const short8*)(W + (size_t)(bn + row) * 1024 + (t_) * 64 + sc8);    \
        } }

    #define OWRITET() {                                                                     \
        _Pragma("unroll")                                                                   \
        for (int i = 0; i < 2; ++i) {                                                       \
            int row = i * 32 + srow;                                                        \
            *(short8*)((char*)sm + row * 128 + (scb ^ ((row & 7) << 4))) = areg[i];         \
        }                                                                                   \
        _Pragma("unroll")                                                                   \
        for (int i = 0; i < 4; ++i) {                                                       \
            int row = i * 32 + srow;                                                        \
            *(short8*)((char*)(sm + 4096) + row * 128 + (scb ^ ((row & 7) << 4))) = wreg[i]; \
        } }

    OLOADT(0);
    #pragma unroll 1
    for (int t = 0; t < 16; ++t) {
        OWRITET();
        __syncthreads();
        if (t < 15) OLOADT(t + 1);

        #pragma unroll
        for (int kk = 0; kk < 2; ++kk) {
            const int c0 = kk * 32 + hi * 8;
            short8 af[2], bf[4];
            #pragma unroll
            for (int mi = 0; mi < 2; ++mi)
                af[mi] = frag128(sm, wr * 32 + mi * 16 + lo, c0);
            #pragma unroll
            for (int ni = 0; ni < 4; ++ni)
                bf[ni] = frag128(sm + 4096, wc * 64 + ni * 16 + lo, c0);
            #pragma unroll
            for (int mi = 0; mi < 2; ++mi)
                #pragma unroll
                for (int ni = 0; ni < 4; ++ni)
                    acc[mi][ni] = MFMA16(af[mi], bf[ni], acc[mi][ni]);
        }
        __syncthreads();
    }
    #undef OLOADT
    #undef OWRITET

    #pragma unroll
    for (int mi = 0; mi < 2; ++mi)
        #pragma unroll
        for (int ni = 0; ni < 4; ++ni)
            #pragma unroll
            for (int j = 0; j < 4; ++j) {
                int m = bm + wr * 32 + mi * 16 + hi * 4 + j;
                int n = bn + wc * 64 + ni * 16 + lo;
                O[(size_t)m * 1024 + n] = acc[mi][ni][j];
            }
}

// ---------------------------------------------------------------------------
// Flash attention (r17). 512 thr = 8 waves, QBLK=128 (16 q-rows/wave), KVBLK=128,
// LDS double-buffer (64 KB) -> ONE barrier per tile. Swapped QK^T, exp2-domain
// in-register softmax (HW v_exp_f32), defer-max THR=8, zero-C MFMA s4 init.
// Grid 512 (XCD-chunked, 2 bh per XCD).
// ---------------------------------------------------------------------------
__global__ __launch_bounds__(512, 4) void attn_fwd(
    const ushort* __restrict__ Q, const ushort* __restrict__ K, const ushort* __restrict__ Vt,
    const int* __restrict__ mask, ushort* __restrict__ ctx)
{
    const int tid = threadIdx.x;
    const int w = tid >> 6, l = tid & 63;
    const int hi = l >> 4, lo = l & 15;
    const int id  = blockIdx.x;
    const int nid = (id & 7) * 64 + (id >> 3);     // 8 XCDs x 64 blocks
    const int bh  = nid >> 4;
    const int q0  = (nid & 15) * 128;
    const int b   = bh >> 4, h = bh & 15;

    __shared__ ushort sm[2][16384];  // per buf: K [128][64] swz @0; V [64][128] swz @8192
    __shared__ int mflag;

    if (tid == 0) mflag = 1;
    __syncthreads();
    {
        int4 m0 = ((const int4*)(mask + b * SEQ))[tid];
        if (!(m0.x && m0.y && m0.z && m0.w)) mflag = 0;
    }

    const ushort* Qh = Q  + (size_t)bh * HSTR;
    const ushort* Kh = K  + (size_t)bh * HSTR;
    const ushort* Vh = Vt + (size_t)bh * HSTR;     // [dk][s]

    short8 qf[2];
    #pragma unroll
    for (int kk = 0; kk < 2; ++kk)
        qf[kk] = *(const short8*)(Qh + (size_t)(q0 + w * 16 + lo) * DKD + kk * 32 + hi * 8);

    f32x4 acc_o[4] = {};
    float m_run = -INFINITY, l_run = 0.0f;

    const int kr = tid >> 3;               // 0..63
    const int kc = (tid & 7) << 3;
    const int vr = tid >> 4;               // 0..31
    const int vkpb = (tid & 15) << 4;

    short8  kreg[2];
    short4v vreg0[2], vreg1[2];

    #define LOADT(kt_) {                                                                   \
        _Pragma("unroll")                                                                  \
        for (int i = 0; i < 2; ++i)                                                        \
            kreg[i] = *(const short8*)(Kh + (size_t)((kt_) * 128 + i * 64 + kr) * DKD + kc); \
        _Pragma("unroll")                                                                  \
        for (int i = 0; i < 2; ++i) {                                                      \
            const ushort* vp = Vh + (size_t)(i * 32 + vr) * SEQ + (kt_) * 128 + ((tid >> 2) & 3) * 32 + (tid & 3) * 4; \
            vreg0[i] = *(const short4v*)(vp);                                              \
            vreg1[i] = *(const short4v*)(vp + 16); } }

    #define WRITET(buf_) {                                                                 \
        _Pragma("unroll")                                                                  \
        for (int i = 0; i < 2; ++i) {                                                      \
            int r = i * 64 + kr;                                                           \
            *(short8*)((char*)sm[buf_] + r * 128 + ((kc * 2) ^ ((r & 7) << 4))) = kreg[i]; } \
        _Pragma("unroll")                                                                  \
        for (int i = 0; i < 2; ++i) {                                                      \
            int r = i * 32 + vr;                                                           \
            char* p = (char*)(sm[buf_] + 8192) + r * 256 + (vkpb ^ ((r & 7) << 4));        \
            *(short4v*)(p)     = vreg0[i];                                                 \
            *(short4v*)(p + 8) = vreg1[i]; } }

    LOADT(0); WRITET(0);
    __syncthreads();                       // buf0 staged + mflag final
    const bool allones = (mflag != 0);
    const f32x4 zf = {};

    #define HALF(nb_) {                                                                    \
        f32x4* s = s4 + 4 * (nb_);                                                         \
        if (!allones) {                                                                    \
            const int* mrow = mask + b * SEQ + kt * 128 + (nb_) * 64 + hi * 4;             \
            _Pragma("unroll")                                                              \
            for (int ni = 0; ni < 4; ++ni) {                                               \
                int4 mv = *(const int4*)(mrow + ni * 16);                                  \
                s[ni][0] = mv.x ? s[ni][0] : -1e9f;                                        \
                s[ni][1] = mv.y ? s[ni][1] : -1e9f;                                        \
                s[ni][2] = mv.z ? s[ni][2] : -1e9f;                                        \
                s[ni][3] = mv.w ? s[ni][3] : -1e9f;                                        \
            }                                                                              \
        }                                                                                  \
        float t0 = fmaxf(fmaxf(s[0][0], s[0][1]), fmaxf(s[0][2], s[0][3]));                \
        float t1 = fmaxf(fmaxf(s[1][0], s[1][1]), fmaxf(s[1][2], s[1][3]));                \
        float t2 = fmaxf(fmaxf(s[2][0], s[2][1]), fmaxf(s[2][2], s[2][3]));                \
        float t3 = fmaxf(fmaxf(s[3][0], s[3][1]), fmaxf(s[3][2], s[3][3]));                \
        float t = fmaxf(fmaxf(t0, t1), fmaxf(t2, t3));                                     \
        t = fmaxf(t, __shfl_xor(t, 16));                                                   \
        t = fmaxf(t, __shfl_xor(t, 32));                                                   \
        if (!__all(t <= m_run + 8.0f)) {   /* defer-max: rescale only on real growth */    \
            float mnew = fmaxf(m_run, t);                                                  \
            float c = EXP2F(m_run - mnew);                                                 \
            m_run = mnew;                                                                  \
            l_run *= c;                                                                    \
            float cj[4];                                                                   \
            _Pragma("unroll")                                                              \
            for (int j = 0; j < 4; ++j) cj[j] = __shfl(c, (l & 48) | (hi * 4 + j));        \
            _Pragma("unroll")                                                              \
            for (int ni = 0; ni < 4; ++ni)                                                 \
                _Pragma("unroll")                                                          \
                for (int j = 0; j < 4; ++j) acc_o[ni][j] *= cj[j];                         \
        }                                                                                  \
        float rsA = 0.0f;                                                                  \
        _Pragma("unroll")                                                                  \
        for (int ni = 0; ni < 4; ++ni) {                                                   \
            _Pragma("unroll")                                                              \
            for (int j = 0; j < 4; ++j) s[ni][j] = EXP2F(s[ni][j] - m_run);                \
            rsA += (s[ni][0] + s[ni][1]) + (s[ni][2] + s[ni][3]);                          \
        }                                                                                  \
        rsA += __shfl_xor(rsA, 16);                                                        \
        rsA += __shfl_xor(rsA, 32);                                                        \
        l_run += rsA;                                                                      \
        short8 pa[2];                                                                      \
        _Pragma("unroll")                                                                  \
        for (int kk = 0; kk < 2; ++kk) {                                                   \
            _Pragma("unroll")                                                              \
            for (int j = 0; j < 4; ++j) {                                                  \
                pa[kk][j]     = (short)f2bf(s[2 * kk][j]);                                 \
                pa[kk][4 + j] = (short)f2bf(s[2 * kk + 1][j]);                             \
            }                                                                              \
        }                                                                                  \
        __builtin_amdgcn_s_setprio(1);                                                     \
        _Pragma("unroll")                                                                  \
        for (int kk = 0; kk < 2; ++kk) {                                                   \
            const int c0 = ((nb_) * 2 + kk) * 32 + hi * 8;                                 \
            _Pragma("unroll")                                                              \
            for (int ni = 0; ni < 4; ++ni) {                                               \
                short8 vf = frag256(vb, ni * 16 + lo, c0);                                 \
                acc_o[ni] = MFMA16(pa[kk], vf, acc_o[ni]);                                 \
            }                                                                              \
        }                                                                                  \
        __builtin_amdgcn_s_setprio(0); }

    #pragma unroll 1
    for (int kt = 0; kt < 16; ++kt) {
        const int cur = kt & 1;
        const ushort* kb = sm[cur];
        const ushort* vb = sm[cur] + 8192;

        if (kt < 15) LOADT(kt + 1);        // global->regs, lands under QK^T+SM(A)

        // QK^T: s4[ni] C-layout: kv = ni*16 + hi*4 + j, q = lo. Zero-C init.
        f32x4 s4[8];
        __builtin_amdgcn_s_setprio(1);
        #pragma unroll
        for (int ni = 0; ni < 8; ++ni)
            s4[ni] = MFMA16(frag128(kb, ni * 16 + lo, hi * 8), qf[0], zf);
        #pragma unroll
        for (int ni = 0; ni < 8; ++ni)
            s4[ni] = MFMA16(frag128(kb, ni * 16 + lo, 32 + hi * 8), qf[1], s4[ni]);
        __builtin_amdgcn_s_setprio(0);

        HALF(0)
        if (kt < 15) WRITET(cur ^ 1);      // regs->other buffer
        HALF(1)

        __syncthreads();                   // single barrier: buf[cur] reads + buf[cur^1] writes done
    }
    #undef HALF
    #undef LOADT
    #undef WRITET

    float inv = 1.0f / l_run;
    float invj[4];
    #pragma unroll
    for (int j = 0; j < 4; ++j)
        invj[j] = __shfl(inv, (l & 48) | (hi * 4 + j));
    #pragma unroll
    for (int ni = 0; ni < 4; ++ni)
        #pragma unroll
        for (int j = 0; j < 4; ++j) {
            int qg = q0 + w * 16 + hi * 4 + j;
            ctx[(size_t)(b * SEQ + qg) * D_MODEL + h * DKD + ni * 16 + lo] = f2bf(acc_o[ni][j] * invj[j]);
        }
}

__global__ void ws_sentinel(float* __restrict__ out, int n, float code) {
    int i = blockIdx.x * blockDim.x + threadIdx.x;
    if (i < n) out[i] = (i == 0) ? code : 0.0f;
}

// ---------------------------------------------------------------------------
extern "C" void kernel_launch(void* const* d_in, const int* in_sizes, int n_in,
                              void* d_out, int out_size, void* d_ws, size_t ws_size,
                              hipStream_t stream) {
    const float* q    = (const float*)d_in[0];
    const float* k    = (const float*)d_in[1];
    const float* v    = (const float*)d_in[2];
    const int*   mask = (const int*)d_in[3];
    const float* wq   = (const float*)d_in[4];
    const float* wk   = (const float*)d_in[5];
    const float* wv   = (const float*)d_in[6];
    const float* wo   = (const float*)d_in[7];
    float* out = (float*)d_out;

    if (ws_size < (size_t)33554432) {
        float code = 100.0f + (float)(ws_size >> 20);
        ws_sentinel<<<(out_size + 255) / 256, 256, 0, stream>>>(out, out_size, code);
        return;
    }

    ushort* ws = (ushort*)d_ws;
    ushort* Qb = ws;                       // [bh][s][dk] bf16 (scaled QSCALE); later: wo bf16
    ushort* Kb = ws + 4194304;             // [bh][s][dk]
    ushort* Vb = ws + 8388608;             // [bh][dk][s]  (transposed)
    ushort* Cb = ws + 12582912;            // first: wq/wk/wv bf16; then context [b,s,d] bf16
    ushort* qk16 = (ushort*)d_out;         // scratch: q-bf16 [0,4M), k-bf16 [4M,8M)
                                           // (overwritten by gemm_o's final f32 output)

    dim3 blk(256, 1, 1);
    cvt_w<<<dim3(512, 3), blk, 0, stream>>>(wq, wk, wv, Cb);
    cvt_in<<<dim3(2048, 2), blk, 0, stream>>>(q, k, qk16);
    gemm_qkv<<<dim3(32, 8, 3), blk, 0, stream>>>(
        qk16, qk16 + 4194304, v, Cb, Cb + 1048576, Cb + 2097152, Qb, Kb, Vb);
    attn_fwd<<<dim3(512, 1, 1), dim3(512, 1, 1), 0, stream>>>(Qb, Kb, Vb, mask, Cb);
    cvt_w<<<dim3(512, 1), blk, 0, stream>>>(wo, wo, wo, Qb);
    gemm_o<<<dim3(64, 8), blk, 0, stream>>>(Cb, Qb, out);
}

// Round 25
// 121.363 us; speedup vs baseline: 1.0545x; 1.0545x over previous
//
#include <hip/hip_runtime.h>
#include <hip/hip_bf16.h>

// MHA forward. f32 inputs (+int32 mask), f32 output; bf16 internal pipeline.
// B=2, S=2048, D_MODEL=1024, H=16, DK=64.
// FINAL = round-20 configuration (best measured: 121.4 us, absmax 1.46e-3).
// [cvt weights->bf16] -> [QKV proj GEMM z=3 (Q scaled 0.125*log2e; V transposed
// via LDS-transpose epilogue), T14 prefetch] -> [flash attn: 8-wave QBLK=128,
// LDS dbuf 1-barrier/tile, swapped QK^T, HW v_exp_f32 exp2-domain softmax,
// defer-max] -> [cvt wo] -> [O proj].

typedef short short8  __attribute__((ext_vector_type(8)));
typedef short short4v __attribute__((ext_vector_type(4)));
typedef float f32x4   __attribute__((ext_vector_type(4)));

#define D_MODEL 1024
#define SEQ     2048
#define NHEAD   16
#define DKD     64
#define HSTR    (SEQ * DKD)
#define QSCALE  0.1803368801111204f   // 0.125 * log2(e): exp2-domain softmax
#define EXP2F(x) __builtin_amdgcn_exp2f(x)   // raw v_exp_f32 (base-2 HW exp)

#define MFMA16(a, b, c) __builtin_amdgcn_mfma_f32_16x16x32_bf16((a), (b), (c), 0, 0, 0)

__device__ __forceinline__ ushort f2bf(float f) {
    __hip_bfloat16 h = __float2bfloat16(f);   // RNE
    return __builtin_bit_cast(ushort, h);
}

__device__ __forceinline__ short8 frag128(const ushort* base, int row, int c0) {
    int cb = (c0 * 2) ^ ((row & 7) << 4);
    return *(const short8*)((const char*)base + row * 128 + cb);
}
__device__ __forceinline__ short8 frag256(const ushort* base, int row, int c0) {
    int cb = (c0 * 2) ^ ((row & 7) << 4);
    return *(const short8*)((const char*)base + row * 256 + cb);
}

// ---------------------------------------------------------------------------
// f32 -> bf16 weight pre-convert: 1M elems per z-slice. grid (512, nz) x 256.
// ---------------------------------------------------------------------------
__global__ __launch_bounds__(256) void cvt_w(
    const float* __restrict__ s0, const float* __restrict__ s1, const float* __restrict__ s2,
    ushort* __restrict__ dst)
{
    const int z = blockIdx.y;
    const float* s = (z == 0) ? s0 : ((z == 1) ? s1 : s2);
    ushort* d = dst + (size_t)z * 1048576;
    const int i = (blockIdx.x * 256 + threadIdx.x) * 8;
    f32x4 a = *(const f32x4*)(s + i);
    f32x4 b = *(const f32x4*)(s + i + 4);
    short8 o;
    #pragma unroll
    for (int u = 0; u < 4; ++u) { o[u] = (short)f2bf(a[u]); o[4 + u] = (short)f2bf(b[u]); }
    *(short8*)(d + i) = o;
}

// ---------------------------------------------------------------------------
// GEMM: C[4096][1024] = A * W^T. Tile 128x128, BK=64, T14 1-deep prefetch. W bf16.
// LAYOUT 0 (QKV): z==0 Q (scaled, head-split); z==1 K (head-split);
//                 z==2 V (transposed [bh][dk][s] via LDS epilogue).
// LAYOUT 1: plain f32 out[m*1024+n] (O-proj).
// ---------------------------------------------------------------------------
template<int LAYOUT, int A_BF16>
__global__ __launch_bounds__(256, 3) void gemm_nt(
    const void* __restrict__ A0, const void* __restrict__ A1, const void* __restrict__ A2,
    const ushort* __restrict__ W0, const ushort* __restrict__ W1, const ushort* __restrict__ W2,
    void* __restrict__ O0, void* __restrict__ O1, void* __restrict__ O2)
{
    const int z = blockIdx.z;
    const void*   A = (z == 0) ? A0 : ((z == 1) ? A1 : A2);
    const ushort* W = (z == 0) ? W0 : ((z == 1) ? W1 : W2);
    void* O         = (z == 0) ? O0 : ((z == 1) ? O1 : O2);

    const int bm = blockIdx.x * 128;
    const int bn = blockIdx.y * 128;
    const int tid = threadIdx.x;
    const int w = tid >> 6, l = tid & 63;
    const int wr = w >> 1, wc = w & 1;

    __shared__ ushort sm[16384];

    f32x4 acc[4][4] = {};
    short8 areg[4], wreg[4];
    const int srow = tid >> 3;
    const int sc8  = (tid & 7) << 3;
    const int scb  = (sc8 * 2);

    #define GLOADT(t_) {                                                                    \
        _Pragma("unroll")                                                                   \
        for (int i = 0; i < 4; ++i) {                                                       \
            int row = i * 32 + srow;                                                        \
            if (A_BF16) {                                                                   \
                areg[i] = *(const short8*)((const ushort*)A + (size_t)(bm + row) * 1024 + (t_) * 64 + sc8); \
            } else {                                                                        \
                const float* ap = (const float*)A + (size_t)(bm + row) * 1024 + (t_) * 64 + sc8; \
                f32x4 x0 = *(const f32x4*)ap, x1 = *(const f32x4*)(ap + 4);                 \
                _Pragma("unroll")                                                           \
                for (int u = 0; u < 4; ++u) { areg[i][u] = (short)f2bf(x0[u]); areg[i][4 + u] = (short)f2bf(x1[u]); } \
            }                                                                               \
            wreg[i] = *(const short8*)(W + (size_t)(bn + row) * 1024 + (t_) * 64 + sc8);    \
        } }

    #define GWRITET() {                                                                     \
        _Pragma("unroll")                                                                   \
        for (int i = 0; i < 4; ++i) {                                                       \
            int row = i * 32 + srow;                                                        \
            int cb  = scb ^ ((row & 7) << 4);                                               \
            *(short8*)((char*)sm + row * 128 + cb) = areg[i];                               \
            *(short8*)((char*)(sm + 8192) + row * 128 + cb) = wreg[i];                      \
        } }

    GLOADT(0);
    #pragma unroll 1
    for (int t = 0; t < 16; ++t) {
        GWRITET();
        __syncthreads();
        if (t < 15) GLOADT(t + 1);

        #pragma unroll
        for (int kk = 0; kk < 2; ++kk) {
            const int c0 = kk * 32 + ((l >> 4) << 3);
            short8 af[4], bf[4];
            #pragma unroll
            for (int mi = 0; mi < 4; ++mi)
                af[mi] = frag128(sm, wr * 64 + mi * 16 + (l & 15), c0);
            #pragma unroll
            for (int ni = 0; ni < 4; ++ni)
                bf[ni] = frag128(sm + 8192, wc * 64 + ni * 16 + (l & 15), c0);
            #pragma unroll
            for (int mi = 0; mi < 4; ++mi)
                #pragma unroll
                for (int ni = 0; ni < 4; ++ni)
                    acc[mi][ni] = MFMA16(af[mi], bf[ni], acc[mi][ni]);
        }
        __syncthreads();
    }
    #undef GLOADT
    #undef GWRITET

    if (LAYOUT == 0 && z == 2) {
        // V epilogue: transpose in LDS, write [bh][dk][s] with 128B-contiguous runs.
        #pragma unroll
        for (int mi = 0; mi < 4; ++mi) {
            #pragma unroll
            for (int ni = 0; ni < 4; ++ni) {
                int n_l = wc * 64 + ni * 16 + (l & 15);
                int m0  = wr * 64 + mi * 16 + ((l >> 4) << 2);
                short4v v4;
                #pragma unroll
                for (int j = 0; j < 4; ++j) v4[j] = (short)f2bf(acc[mi][ni][j]);
                *(short4v*)((char*)sm + n_l * 256 + ((m0 * 2) ^ ((n_l & 7) << 4))) = v4;
            }
        }
        __syncthreads();
        const int row = tid >> 1, half = tid & 1;
        const int n_g = bn + row;
        const int bb  = bm >> 11;
        ushort* Op = (ushort*)O + (size_t)(bb * NHEAD + (n_g >> 6)) * HSTR
                     + (size_t)(n_g & 63) * SEQ + (bm & 2047) + half * 64;
        #pragma unroll
        for (int u = 0; u < 8; ++u) {
            short8 c = *(const short8*)((char*)sm + row * 256
                        + (((half * 64 + u * 8) * 2) ^ ((row & 7) << 4)));
            *(short8*)(Op + u * 8) = c;
        }
        return;
    }

    const float sc = (LAYOUT == 0 && z == 0) ? QSCALE : 1.0f;
    #pragma unroll
    for (int mi = 0; mi < 4; ++mi) {
        #pragma unroll
        for (int ni = 0; ni < 4; ++ni) {
            #pragma unroll
            for (int j = 0; j < 4; ++j) {
                int m = bm + wr * 64 + mi * 16 + ((l >> 4) << 2) + j;
                int n = bn + wc * 64 + ni * 16 + (l & 15);
                if (LAYOUT == 0) {
                    int b = m >> 11, s = m & 2047, h = n >> 6, dk = n & 63;
                    ((ushort*)O)[(size_t)(b * NHEAD + h) * HSTR + s * DKD + dk] = f2bf(acc[mi][ni][j] * sc);
                } else {
                    ((float*)O)[(size_t)m * 1024 + n] = acc[mi][ni][j];
                }
            }
        }
    }
}

// ---------------------------------------------------------------------------
// Flash attention. 512 thr = 8 waves, QBLK=128 (16 q-rows/wave), KVBLK=128,
// LDS double-buffer (64 KB) -> ONE barrier per tile. Swapped QK^T, exp2-domain
// in-register softmax (HW v_exp_f32), defer-max THR=8, zero-C MFMA s4 init.
// Grid 512 (XCD-chunked, 2 bh per XCD).
// ---------------------------------------------------------------------------
__global__ __launch_bounds__(512, 4) void attn_fwd(
    const ushort* __restrict__ Q, const ushort* __restrict__ K, const ushort* __restrict__ Vt,
    const int* __restrict__ mask, ushort* __restrict__ ctx)
{
    const int tid = threadIdx.x;
    const int w = tid >> 6, l = tid & 63;
    const int hi = l >> 4, lo = l & 15;
    const int id  = blockIdx.x;
    const int nid = (id & 7) * 64 + (id >> 3);     // 8 XCDs x 64 blocks
    const int bh  = nid >> 4;
    const int q0  = (nid & 15) * 128;
    const int b   = bh >> 4, h = bh & 15;

    __shared__ ushort sm[2][16384];  // per buf: K [128][64] swz @0; V [64][128] swz @8192
    __shared__ int mflag;

    if (tid == 0) mflag = 1;
    __syncthreads();
    {
        int4 m0 = ((const int4*)(mask + b * SEQ))[tid];
        if (!(m0.x && m0.y && m0.z && m0.w)) mflag = 0;
    }

    const ushort* Qh = Q  + (size_t)bh * HSTR;
    const ushort* Kh = K  + (size_t)bh * HSTR;
    const ushort* Vh = Vt + (size_t)bh * HSTR;     // [dk][s]

    short8 qf[2];
    #pragma unroll
    for (int kk = 0; kk < 2; ++kk)
        qf[kk] = *(const short8*)(Qh + (size_t)(q0 + w * 16 + lo) * DKD + kk * 32 + hi * 8);

    f32x4 acc_o[4] = {};
    float m_run = -INFINITY, l_run = 0.0f;

    const int kr = tid >> 3;               // 0..63
    const int kc = (tid & 7) << 3;
    const int vr = tid >> 4;               // 0..31
    const int vkpb = (tid & 15) << 4;

    short8  kreg[2];
    short4v vreg0[2], vreg1[2];

    #define LOADT(kt_) {                                                                   \
        _Pragma("unroll")                                                                  \
        for (int i = 0; i < 2; ++i)                                                        \
            kreg[i] = *(const short8*)(Kh + (size_t)((kt_) * 128 + i * 64 + kr) * DKD + kc); \
        _Pragma("unroll")                                                                  \
        for (int i = 0; i < 2; ++i) {                                                      \
            const ushort* vp = Vh + (size_t)(i * 32 + vr) * SEQ + (kt_) * 128 + ((tid >> 2) & 3) * 32 + (tid & 3) * 4; \
            vreg0[i] = *(const short4v*)(vp);                                              \
            vreg1[i] = *(const short4v*)(vp + 16); } }

    #define WRITET(buf_) {                                                                 \
        _Pragma("unroll")                                                                  \
        for (int i = 0; i < 2; ++i) {                                                      \
            int r = i * 64 + kr;                                                           \
            *(short8*)((char*)sm[buf_] + r * 128 + ((kc * 2) ^ ((r & 7) << 4))) = kreg[i]; } \
        _Pragma("unroll")                                                                  \
        for (int i = 0; i < 2; ++i) {                                                      \
            int r = i * 32 + vr;                                                           \
            char* p = (char*)(sm[buf_] + 8192) + r * 256 + (vkpb ^ ((r & 7) << 4));        \
            *(short4v*)(p)     = vreg0[i];                                                 \
            *(short4v*)(p + 8) = vreg1[i]; } }

    LOADT(0); WRITET(0);
    __syncthreads();                       // buf0 staged + mflag final
    const bool allones = (mflag != 0);
    const f32x4 zf = {};

    #define HALF(nb_) {                                                                    \
        f32x4* s = s4 + 4 * (nb_);                                                         \
        if (!allones) {                                                                    \
            const int* mrow = mask + b * SEQ + kt * 128 + (nb_) * 64 + hi * 4;             \
            _Pragma("unroll")                                                              \
            for (int ni = 0; ni < 4; ++ni) {                                               \
                int4 mv = *(const int4*)(mrow + ni * 16);                                  \
                s[ni][0] = mv.x ? s[ni][0] : -1e9f;                                        \
                s[ni][1] = mv.y ? s[ni][1] : -1e9f;                                        \
                s[ni][2] = mv.z ? s[ni][2] : -1e9f;                                        \
                s[ni][3] = mv.w ? s[ni][3] : -1e9f;                                        \
            }                                                                              \
        }                                                                                  \
        float t0 = fmaxf(fmaxf(s[0][0], s[0][1]), fmaxf(s[0][2], s[0][3]));                \
        float t1 = fmaxf(fmaxf(s[1][0], s[1][1]), fmaxf(s[1][2], s[1][3]));                \
        float t2 = fmaxf(fmaxf(s[2][0], s[2][1]), fmaxf(s[2][2], s[2][3]));                \
        float t3 = fmaxf(fmaxf(s[3][0], s[3][1]), fmaxf(s[3][2], s[3][3]));                \
        float t = fmaxf(fmaxf(t0, t1), fmaxf(t2, t3));                                     \
        t = fmaxf(t, __shfl_xor(t, 16));                                                   \
        t = fmaxf(t, __shfl_xor(t, 32));                                                   \
        if (!__all(t <= m_run + 8.0f)) {   /* defer-max: rescale only on real growth */    \
            float mnew = fmaxf(m_run, t);                                                  \
            float c = EXP2F(m_run - mnew);                                                 \
            m_run = mnew;                                                                  \
            l_run *= c;                                                                    \
            float cj[4];                                                                   \
            _Pragma("unroll")                                                              \
            for (int j = 0; j < 4; ++j) cj[j] = __shfl(c, (l & 48) | (hi * 4 + j));        \
            _Pragma("unroll")                                                              \
            for (int ni = 0; ni < 4; ++ni)                                                 \
                _Pragma("unroll")                                                          \
                for (int j = 0; j < 4; ++j) acc_o[ni][j] *= cj[j];                         \
        }                                                                                  \
        float rsA = 0.0f;                                                                  \
        _Pragma("unroll")                                                                  \
        for (int ni = 0; ni < 4; ++ni) {                                                   \
            _Pragma("unroll")                                                              \
            for (int j = 0; j < 4; ++j) s[ni][j] = EXP2F(s[ni][j] - m_run);                \
            rsA += (s[ni][0] + s[ni][1]) + (s[ni][2] + s[ni][3]);                          \
        }                                                                                  \
        rsA += __shfl_xor(rsA, 16);                                                        \
        rsA += __shfl_xor(rsA, 32);                                                        \
        l_run += rsA;                                                                      \
        short8 pa[2];                                                                      \
        _Pragma("unroll")                                                                  \
        for (int kk = 0; kk < 2; ++kk) {                                                   \
            _Pragma("unroll")                                                              \
            for (int j = 0; j < 4; ++j) {                                                  \
                pa[kk][j]     = (short)f2bf(s[2 * kk][j]);                                 \
                pa[kk][4 + j] = (short)f2bf(s[2 * kk + 1][j]);                             \
            }                                                                              \
        }                                                                                  \
        __builtin_amdgcn_s_setprio(1);                                                     \
        _Pragma("unroll")                                                                  \
        for (int kk = 0; kk < 2; ++kk) {                                                   \
            const int c0 = ((nb_) * 2 + kk) * 32 + hi * 8;                                 \
            _Pragma("unroll")                                                              \
            for (int ni = 0; ni < 4; ++ni) {                                               \
                short8 vf = frag256(vb, ni * 16 + lo, c0);                                 \
                acc_o[ni] = MFMA16(pa[kk], vf, acc_o[ni]);                                 \
            }                                                                              \
        }                                                                                  \
        __builtin_amdgcn_s_setprio(0); }

    #pragma unroll 1
    for (int kt = 0; kt < 16; ++kt) {
        const int cur = kt & 1;
        const ushort* kb = sm[cur];
        const ushort* vb = sm[cur] + 8192;

        if (kt < 15) LOADT(kt + 1);        // global->regs, lands under QK^T+SM(A)

        // QK^T: s4[ni] C-layout: kv = ni*16 + hi*4 + j, q = lo. Zero-C init.
        f32x4 s4[8];
        __builtin_amdgcn_s_setprio(1);
        #pragma unroll
        for (int ni = 0; ni < 8; ++ni)
            s4[ni] = MFMA16(frag128(kb, ni * 16 + lo, hi * 8), qf[0], zf);
        #pragma unroll
        for (int ni = 0; ni < 8; ++ni)
            s4[ni] = MFMA16(frag128(kb, ni * 16 + lo, 32 + hi * 8), qf[1], s4[ni]);
        __builtin_amdgcn_s_setprio(0);

        HALF(0)
        if (kt < 15) WRITET(cur ^ 1);      // regs->other buffer
        HALF(1)

        __syncthreads();                   // single barrier: buf[cur] reads + buf[cur^1] writes done
    }
    #undef HALF
    #undef LOADT
    #undef WRITET

    float inv = 1.0f / l_run;
    float invj[4];
    #pragma unroll
    for (int j = 0; j < 4; ++j)
        invj[j] = __shfl(inv, (l & 48) | (hi * 4 + j));
    #pragma unroll
    for (int ni = 0; ni < 4; ++ni)
        #pragma unroll
        for (int j = 0; j < 4; ++j) {
            int qg = q0 + w * 16 + hi * 4 + j;
            ctx[(size_t)(b * SEQ + qg) * D_MODEL + h * DKD + ni * 16 + lo] = f2bf(acc_o[ni][j] * invj[j]);
        }
}

__global__ void ws_sentinel(float* __restrict__ out, int n, float code) {
    int i = blockIdx.x * blockDim.x + threadIdx.x;
    if (i < n) out[i] = (i == 0) ? code : 0.0f;
}

// ---------------------------------------------------------------------------
extern "C" void kernel_launch(void* const* d_in, const int* in_sizes, int n_in,
                              void* d_out, int out_size, void* d_ws, size_t ws_size,
                              hipStream_t stream) {
    const float* q    = (const float*)d_in[0];
    const float* k    = (const float*)d_in[1];
    const float* v    = (const float*)d_in[2];
    const int*   mask = (const int*)d_in[3];
    const float* wq   = (const float*)d_in[4];
    const float* wk   = (const float*)d_in[5];
    const float* wv   = (const float*)d_in[6];
    const float* wo   = (const float*)d_in[7];
    float* out = (float*)d_out;

    if (ws_size < (size_t)33554432) {
        float code = 100.0f + (float)(ws_size >> 20);
        ws_sentinel<<<(out_size + 255) / 256, 256, 0, stream>>>(out, out_size, code);
        return;
    }

    ushort* ws = (ushort*)d_ws;
    ushort* Qb = ws;                       // [bh][s][dk] bf16 (scaled QSCALE); later: wo bf16
    ushort* Kb = ws + 4194304;             // [bh][s][dk]
    ushort* Vb = ws + 8388608;             // [bh][dk][s]  (transposed)
    ushort* Cb = ws + 12582912;            // first: wq/wk/wv bf16; then context [b,s,d] bf16

    dim3 blk(256, 1, 1);
    cvt_w<<<dim3(512, 3), blk, 0, stream>>>(wq, wk, wv, Cb);
    gemm_nt<0, 0><<<dim3(32, 8, 3), blk, 0, stream>>>(
        q, k, v, Cb, Cb + 1048576, Cb + 2097152, Qb, Kb, Vb);
    attn_fwd<<<dim3(512, 1, 1), dim3(512, 1, 1), 0, stream>>>(Qb, Kb, Vb, mask, Cb);
    cvt_w<<<dim3(512, 1), blk, 0, stream>>>(wo, wo, wo, Qb);
    gemm_nt<1, 1><<<dim3(32, 8, 1), blk, 0, stream>>>(
        Cb, Cb, Cb, Qb, Qb, Qb, out, out, out);
}

// Round 26
// 121.277 us; speedup vs baseline: 1.0553x; 1.0007x over previous
//
#include <hip/hip_runtime.h>
#include <hip/hip_bf16.h>

// MHA forward. f32 inputs (+int32 mask), f32 output; bf16 internal pipeline.
// B=2, S=2048, D_MODEL=1024, H=16, DK=64.
// R26 = r20 + QKV launch_bounds (256,3)->(256,2): grid is 3 blocks/CU anyway,
// so raising the VGPR cap to 128 is free and lets the compiler keep all 16
// staging loads in flight (was serialized at 76 VGPR -> exposed load latency).
// [cvt weights->bf16] -> [QKV proj GEMM z=3] -> [flash attn r17] -> [cvt wo] -> [O proj].

typedef short short8  __attribute__((ext_vector_type(8)));
typedef short short4v __attribute__((ext_vector_type(4)));
typedef float f32x4   __attribute__((ext_vector_type(4)));

#define D_MODEL 1024
#define SEQ     2048
#define NHEAD   16
#define DKD     64
#define HSTR    (SEQ * DKD)
#define QSCALE  0.1803368801111204f   // 0.125 * log2(e): exp2-domain softmax
#define EXP2F(x) __builtin_amdgcn_exp2f(x)   // raw v_exp_f32 (base-2 HW exp)

#define MFMA16(a, b, c) __builtin_amdgcn_mfma_f32_16x16x32_bf16((a), (b), (c), 0, 0, 0)

__device__ __forceinline__ ushort f2bf(float f) {
    __hip_bfloat16 h = __float2bfloat16(f);   // RNE
    return __builtin_bit_cast(ushort, h);
}

__device__ __forceinline__ short8 frag128(const ushort* base, int row, int c0) {
    int cb = (c0 * 2) ^ ((row & 7) << 4);
    return *(const short8*)((const char*)base + row * 128 + cb);
}
__device__ __forceinline__ short8 frag256(const ushort* base, int row, int c0) {
    int cb = (c0 * 2) ^ ((row & 7) << 4);
    return *(const short8*)((const char*)base + row * 256 + cb);
}

// ---------------------------------------------------------------------------
// f32 -> bf16 weight pre-convert: 1M elems per z-slice. grid (512, nz) x 256.
// ---------------------------------------------------------------------------
__global__ __launch_bounds__(256) void cvt_w(
    const float* __restrict__ s0, const float* __restrict__ s1, const float* __restrict__ s2,
    ushort* __restrict__ dst)
{
    const int z = blockIdx.y;
    const float* s = (z == 0) ? s0 : ((z == 1) ? s1 : s2);
    ushort* d = dst + (size_t)z * 1048576;
    const int i = (blockIdx.x * 256 + threadIdx.x) * 8;
    f32x4 a = *(const f32x4*)(s + i);
    f32x4 b = *(const f32x4*)(s + i + 4);
    short8 o;
    #pragma unroll
    for (int u = 0; u < 4; ++u) { o[u] = (short)f2bf(a[u]); o[4 + u] = (short)f2bf(b[u]); }
    *(short8*)(d + i) = o;
}

// ---------------------------------------------------------------------------
// GEMM: C[4096][1024] = A * W^T. Tile 128x128, BK=64, T14 1-deep prefetch. W bf16.
// LAYOUT 0 (QKV, launch_bounds(256,2)): z==0 Q (scaled, head-split); z==1 K;
//                 z==2 V (transposed [bh][dk][s] via LDS epilogue).
// LAYOUT 1 (O-proj, launch_bounds(256,3)): plain f32 out[m*1024+n].
// ---------------------------------------------------------------------------
template<int LAYOUT, int A_BF16>
__global__ __launch_bounds__(256, (LAYOUT == 0 ? 2 : 3)) void gemm_nt(
    const void* __restrict__ A0, const void* __restrict__ A1, const void* __restrict__ A2,
    const ushort* __restrict__ W0, const ushort* __restrict__ W1, const ushort* __restrict__ W2,
    void* __restrict__ O0, void* __restrict__ O1, void* __restrict__ O2)
{
    const int z = blockIdx.z;
    const void*   A = (z == 0) ? A0 : ((z == 1) ? A1 : A2);
    const ushort* W = (z == 0) ? W0 : ((z == 1) ? W1 : W2);
    void* O         = (z == 0) ? O0 : ((z == 1) ? O1 : O2);

    const int bm = blockIdx.x * 128;
    const int bn = blockIdx.y * 128;
    const int tid = threadIdx.x;
    const int w = tid >> 6, l = tid & 63;
    const int wr = w >> 1, wc = w & 1;

    __shared__ ushort sm[16384];

    f32x4 acc[4][4] = {};
    short8 areg[4], wreg[4];
    const int srow = tid >> 3;
    const int sc8  = (tid & 7) << 3;
    const int scb  = (sc8 * 2);

    #define GLOADT(t_) {                                                                    \
        _Pragma("unroll")                                                                   \
        for (int i = 0; i < 4; ++i) {                                                       \
            int row = i * 32 + srow;                                                        \
            if (A_BF16) {                                                                   \
                areg[i] = *(const short8*)((const ushort*)A + (size_t)(bm + row) * 1024 + (t_) * 64 + sc8); \
            } else {                                                                        \
                const float* ap = (const float*)A + (size_t)(bm + row) * 1024 + (t_) * 64 + sc8; \
                f32x4 x0 = *(const f32x4*)ap, x1 = *(const f32x4*)(ap + 4);                 \
                _Pragma("unroll")                                                           \
                for (int u = 0; u < 4; ++u) { areg[i][u] = (short)f2bf(x0[u]); areg[i][4 + u] = (short)f2bf(x1[u]); } \
            }                                                                               \
            wreg[i] = *(const short8*)(W + (size_t)(bn + row) * 1024 + (t_) * 64 + sc8);    \
        } }

    #define GWRITET() {                                                                     \
        _Pragma("unroll")                                                                   \
        for (int i = 0; i < 4; ++i) {                                                       \
            int row = i * 32 + srow;                                                        \
            int cb  = scb ^ ((row & 7) << 4);                                               \
            *(short8*)((char*)sm + row * 128 + cb) = areg[i];                               \
            *(short8*)((char*)(sm + 8192) + row * 128 + cb) = wreg[i];                      \
        } }

    GLOADT(0);
    #pragma unroll 1
    for (int t = 0; t < 16; ++t) {
        GWRITET();
        __syncthreads();
        if (t < 15) GLOADT(t + 1);

        #pragma unroll
        for (int kk = 0; kk < 2; ++kk) {
            const int c0 = kk * 32 + ((l >> 4) << 3);
            short8 af[4], bf[4];
            #pragma unroll
            for (int mi = 0; mi < 4; ++mi)
                af[mi] = frag128(sm, wr * 64 + mi * 16 + (l & 15), c0);
            #pragma unroll
            for (int ni = 0; ni < 4; ++ni)
                bf[ni] = frag128(sm + 8192, wc * 64 + ni * 16 + (l & 15), c0);
            #pragma unroll
            for (int mi = 0; mi < 4; ++mi)
                #pragma unroll
                for (int ni = 0; ni < 4; ++ni)
                    acc[mi][ni] = MFMA16(af[mi], bf[ni], acc[mi][ni]);
        }
        __syncthreads();
    }
    #undef GLOADT
    #undef GWRITET

    if (LAYOUT == 0 && z == 2) {
        // V epilogue: transpose in LDS, write [bh][dk][s] with 128B-contiguous runs.
        #pragma unroll
        for (int mi = 0; mi < 4; ++mi) {
            #pragma unroll
            for (int ni = 0; ni < 4; ++ni) {
                int n_l = wc * 64 + ni * 16 + (l & 15);
                int m0  = wr * 64 + mi * 16 + ((l >> 4) << 2);
                short4v v4;
                #pragma unroll
                for (int j = 0; j < 4; ++j) v4[j] = (short)f2bf(acc[mi][ni][j]);
                *(short4v*)((char*)sm + n_l * 256 + ((m0 * 2) ^ ((n_l & 7) << 4))) = v4;
            }
        }
        __syncthreads();
        const int row = tid >> 1, half = tid & 1;
        const int n_g = bn + row;
        const int bb  = bm >> 11;
        ushort* Op = (ushort*)O + (size_t)(bb * NHEAD + (n_g >> 6)) * HSTR
                     + (size_t)(n_g & 63) * SEQ + (bm & 2047) + half * 64;
        #pragma unroll
        for (int u = 0; u < 8; ++u) {
            short8 c = *(const short8*)((char*)sm + row * 256
                        + (((half * 64 + u * 8) * 2) ^ ((row & 7) << 4)));
            *(short8*)(Op + u * 8) = c;
        }
        return;
    }

    const float sc = (LAYOUT == 0 && z == 0) ? QSCALE : 1.0f;
    #pragma unroll
    for (int mi = 0; mi < 4; ++mi) {
        #pragma unroll
        for (int ni = 0; ni < 4; ++ni) {
            #pragma unroll
            for (int j = 0; j < 4; ++j) {
                int m = bm + wr * 64 + mi * 16 + ((l >> 4) << 2) + j;
                int n = bn + wc * 64 + ni * 16 + (l & 15);
                if (LAYOUT == 0) {
                    int b = m >> 11, s = m & 2047, h = n >> 6, dk = n & 63;
                    ((ushort*)O)[(size_t)(b * NHEAD + h) * HSTR + s * DKD + dk] = f2bf(acc[mi][ni][j] * sc);
                } else {
                    ((float*)O)[(size_t)m * 1024 + n] = acc[mi][ni][j];
                }
            }
        }
    }
}

// ---------------------------------------------------------------------------
// Flash attention (r17). 512 thr = 8 waves, QBLK=128 (16 q-rows/wave), KVBLK=128,
// LDS double-buffer (64 KB) -> ONE barrier per tile. Swapped QK^T, exp2-domain
// in-register softmax (HW v_exp_f32), defer-max THR=8, zero-C MFMA s4 init.
// Grid 512 (XCD-chunked, 2 bh per XCD).
// ---------------------------------------------------------------------------
__global__ __launch_bounds__(512, 4) void attn_fwd(
    const ushort* __restrict__ Q, const ushort* __restrict__ K, const ushort* __restrict__ Vt,
    const int* __restrict__ mask, ushort* __restrict__ ctx)
{
    const int tid = threadIdx.x;
    const int w = tid >> 6, l = tid & 63;
    const int hi = l >> 4, lo = l & 15;
    const int id  = blockIdx.x;
    const int nid = (id & 7) * 64 + (id >> 3);     // 8 XCDs x 64 blocks
    const int bh  = nid >> 4;
    const int q0  = (nid & 15) * 128;
    const int b   = bh >> 4, h = bh & 15;

    __shared__ ushort sm[2][16384];  // per buf: K [128][64] swz @0; V [64][128] swz @8192
    __shared__ int mflag;

    if (tid == 0) mflag = 1;
    __syncthreads();
    {
        int4 m0 = ((const int4*)(mask + b * SEQ))[tid];
        if (!(m0.x && m0.y && m0.z && m0.w)) mflag = 0;
    }

    const ushort* Qh = Q  + (size_t)bh * HSTR;
    const ushort* Kh = K  + (size_t)bh * HSTR;
    const ushort* Vh = Vt + (size_t)bh * HSTR;     // [dk][s]

    short8 qf[2];
    #pragma unroll
    for (int kk = 0; kk < 2; ++kk)
        qf[kk] = *(const short8*)(Qh + (size_t)(q0 + w * 16 + lo) * DKD + kk * 32 + hi * 8);

    f32x4 acc_o[4] = {};
    float m_run = -INFINITY, l_run = 0.0f;

    const int kr = tid >> 3;               // 0..63
    const int kc = (tid & 7) << 3;
    const int vr = tid >> 4;               // 0..31
    const int vkpb = (tid & 15) << 4;

    short8  kreg[2];
    short4v vreg0[2], vreg1[2];

    #define LOADT(kt_) {                                                                   \
        _Pragma("unroll")                                                                  \
        for (int i = 0; i < 2; ++i)                                                        \
            kreg[i] = *(const short8*)(Kh + (size_t)((kt_) * 128 + i * 64 + kr) * DKD + kc); \
        _Pragma("unroll")                                                                  \
        for (int i = 0; i < 2; ++i) {                                                      \
            const ushort* vp = Vh + (size_t)(i * 32 + vr) * SEQ + (kt_) * 128 + ((tid >> 2) & 3) * 32 + (tid & 3) * 4; \
            vreg0[i] = *(const short4v*)(vp);                                              \
            vreg1[i] = *(const short4v*)(vp + 16); } }

    #define WRITET(buf_) {                                                                 \
        _Pragma("unroll")                                                                  \
        for (int i = 0; i < 2; ++i) {                                                      \
            int r = i * 64 + kr;                                                           \
            *(short8*)((char*)sm[buf_] + r * 128 + ((kc * 2) ^ ((r & 7) << 4))) = kreg[i]; } \
        _Pragma("unroll")                                                                  \
        for (int i = 0; i < 2; ++i) {                                                      \
            int r = i * 32 + vr;                                                           \
            char* p = (char*)(sm[buf_] + 8192) + r * 256 + (vkpb ^ ((r & 7) << 4));        \
            *(short4v*)(p)     = vreg0[i];                                                 \
            *(short4v*)(p + 8) = vreg1[i]; } }

    LOADT(0); WRITET(0);
    __syncthreads();                       // buf0 staged + mflag final
    const bool allones = (mflag != 0);
    const f32x4 zf = {};

    #define HALF(nb_) {                                                                    \
        f32x4* s = s4 + 4 * (nb_);                                                         \
        if (!allones) {                                                                    \
            const int* mrow = mask + b * SEQ + kt * 128 + (nb_) * 64 + hi * 4;             \
            _Pragma("unroll")                                                              \
            for (int ni = 0; ni < 4; ++ni) {                                               \
                int4 mv = *(const int4*)(mrow + ni * 16);                                  \
                s[ni][0] = mv.x ? s[ni][0] : -1e9f;                                        \
                s[ni][1] = mv.y ? s[ni][1] : -1e9f;                                        \
                s[ni][2] = mv.z ? s[ni][2] : -1e9f;                                        \
                s[ni][3] = mv.w ? s[ni][3] : -1e9f;                                        \
            }                                                                              \
        }                                                                                  \
        float t0 = fmaxf(fmaxf(s[0][0], s[0][1]), fmaxf(s[0][2], s[0][3]));                \
        float t1 = fmaxf(fmaxf(s[1][0], s[1][1]), fmaxf(s[1][2], s[1][3]));                \
        float t2 = fmaxf(fmaxf(s[2][0], s[2][1]), fmaxf(s[2][2], s[2][3]));                \
        float t3 = fmaxf(fmaxf(s[3][0], s[3][1]), fmaxf(s[3][2], s[3][3]));                \
        float t = fmaxf(fmaxf(t0, t1), fmaxf(t2, t3));                                     \
        t = fmaxf(t, __shfl_xor(t, 16));                                                   \
        t = fmaxf(t, __shfl_xor(t, 32));                                                   \
        if (!__all(t <= m_run + 8.0f)) {   /* defer-max: rescale only on real growth */    \
            float mnew = fmaxf(m_run, t);                                                  \
            float c = EXP2F(m_run - mnew);                                                 \
            m_run = mnew;                                                                  \
            l_run *= c;                                                                    \
            float cj[4];                                                                   \
            _Pragma("unroll")                                                              \
            for (int j = 0; j < 4; ++j) cj[j] = __shfl(c, (l & 48) | (hi * 4 + j));        \
            _Pragma("unroll")                                                              \
            for (int ni = 0; ni < 4; ++ni)                                                 \
                _Pragma("unroll")                                                          \
                for (int j = 0; j < 4; ++j) acc_o[ni][j] *= cj[j];                         \
        }                                                                                  \
        float rsA = 0.0f;                                                                  \
        _Pragma("unroll")                                                                  \
        for (int ni = 0; ni < 4; ++ni) {                                                   \
            _Pragma("unroll")                                                              \
            for (int j = 0; j < 4; ++j) s[ni][j] = EXP2F(s[ni][j] - m_run);                \
            rsA += (s[ni][0] + s[ni][1]) + (s[ni][2] + s[ni][3]);                          \
        }                                                                                  \
        rsA += __shfl_xor(rsA, 16);                                                        \
        rsA += __shfl_xor(rsA, 32);                                                        \
        l_run += rsA;                                                                      \
        short8 pa[2];                                                                      \
        _Pragma("unroll")                                                                  \
        for (int kk = 0; kk < 2; ++kk) {                                                   \
            _Pragma("unroll")                                                              \
            for (int j = 0; j < 4; ++j) {                                                  \
                pa[kk][j]     = (short)f2bf(s[2 * kk][j]);                                 \
                pa[kk][4 + j] = (short)f2bf(s[2 * kk + 1][j]);                             \
            }                                                                              \
        }                                                                                  \
        __builtin_amdgcn_s_setprio(1);                                                     \
        _Pragma("unroll")                                                                  \
        for (int kk = 0; kk < 2; ++kk) {                                                   \
            const int c0 = ((nb_) * 2 + kk) * 32 + hi * 8;                                 \
            _Pragma("unroll")                                                              \
            for (int ni = 0; ni < 4; ++ni) {                                               \
                short8 vf = frag256(vb, ni * 16 + lo, c0);                                 \
                acc_o[ni] = MFMA16(pa[kk], vf, acc_o[ni]);                                 \
            }                                                                              \
        }                                                                                  \
        __builtin_amdgcn_s_setprio(0); }

    #pragma unroll 1
    for (int kt = 0; kt < 16; ++kt) {
        const int cur = kt & 1;
        const ushort* kb = sm[cur];
        const ushort* vb = sm[cur] + 8192;

        if (kt < 15) LOADT(kt + 1);        // global->regs, lands under QK^T+SM(A)

        // QK^T: s4[ni] C-layout: kv = ni*16 + hi*4 + j, q = lo. Zero-C init.
        f32x4 s4[8];
        __builtin_amdgcn_s_setprio(1);
        #pragma unroll
        for (int ni = 0; ni < 8; ++ni)
            s4[ni] = MFMA16(frag128(kb, ni * 16 + lo, hi * 8), qf[0], zf);
        #pragma unroll
        for (int ni = 0; ni < 8; ++ni)
            s4[ni] = MFMA16(frag128(kb, ni * 16 + lo, 32 + hi * 8), qf[1], s4[ni]);
        __builtin_amdgcn_s_setprio(0);

        HALF(0)
        if (kt < 15) WRITET(cur ^ 1);      // regs->other buffer
        HALF(1)

        __syncthreads();                   // single barrier: buf[cur] reads + buf[cur^1] writes done
    }
    #undef HALF
    #undef LOADT
    #undef WRITET

    float inv = 1.0f / l_run;
    float invj[4];
    #pragma unroll
    for (int j = 0; j < 4; ++j)
        invj[j] = __shfl(inv, (l & 48) | (hi * 4 + j));
    #pragma unroll
    for (int ni = 0; ni < 4; ++ni)
        #pragma unroll
        for (int j = 0; j < 4; ++j) {
            int qg = q0 + w * 16 + hi * 4 + j;
            ctx[(size_t)(b * SEQ + qg) * D_MODEL + h * DKD + ni * 16 + lo] = f2bf(acc_o[ni][j] * invj[j]);
        }
}

__global__ void ws_sentinel(float* __restrict__ out, int n, float code) {
    int i = blockIdx.x * blockDim.x + threadIdx.x;
    if (i < n) out[i] = (i == 0) ? code : 0.0f;
}

// ---------------------------------------------------------------------------
extern "C" void kernel_launch(void* const* d_in, const int* in_sizes, int n_in,
                              void* d_out, int out_size, void* d_ws, size_t ws_size,
                              hipStream_t stream) {
    const float* q    = (const float*)d_in[0];
    const float* k    = (const float*)d_in[1];
    const float* v    = (const float*)d_in[2];
    const int*   mask = (const int*)d_in[3];
    const float* wq   = (const float*)d_in[4];
    const float* wk   = (const float*)d_in[5];
    const float* wv   = (const float*)d_in[6];
    const float* wo   = (const float*)d_in[7];
    float* out = (float*)d_out;

    if (ws_size < (size_t)33554432) {
        float code = 100.0f + (float)(ws_size >> 20);
        ws_sentinel<<<(out_size + 255) / 256, 256, 0, stream>>>(out, out_size, code);
        return;
    }

    ushort* ws = (ushort*)d_ws;
    ushort* Qb = ws;                       // [bh][s][dk] bf16 (scaled QSCALE); later: wo bf16
    ushort* Kb = ws + 4194304;             // [bh][s][dk]
    ushort* Vb = ws + 8388608;             // [bh][dk][s]  (transposed)
    ushort* Cb = ws + 12582912;            // first: wq/wk/wv bf16; then context [b,s,d] bf16

    dim3 blk(256, 1, 1);
    cvt_w<<<dim3(512, 3), blk, 0, stream>>>(wq, wk, wv, Cb);
    gemm_nt<0, 0><<<dim3(32, 8, 3), blk, 0, stream>>>(
        q, k, v, Cb, Cb + 1048576, Cb + 2097152, Qb, Kb, Vb);
    attn_fwd<<<dim3(512, 1, 1), dim3(512, 1, 1), 0, stream>>>(Qb, Kb, Vb, mask, Cb);
    cvt_w<<<dim3(512, 1), blk, 0, stream>>>(wo, wo, wo, Qb);
    gemm_nt<1, 1><<<dim3(32, 8, 1), blk, 0, stream>>>(
        Cb, Cb, Cb, Qb, Qb, Qb, out, out, out);
}